// Round 4
// baseline (541.409 us; speedup 1.0000x reference)
//
#include <hip/hip_runtime.h>
#include <hip/hip_bf16.h>
#include <math.h>

typedef __bf16 bf16;
typedef bf16 bf16x2 __attribute__((ext_vector_type(2)));
typedef bf16 bf16x4 __attribute__((ext_vector_type(4)));
typedef bf16 bf16x8 __attribute__((ext_vector_type(8)));
typedef float f32x4 __attribute__((ext_vector_type(4)));

#define T_TOK 4096
#define DDIM  768
#define HDIM  2688
#define NEXP  8
#define RMAX  9216            // max padded pair rows
#define KHALF (HDIM / 2)      // 1344
#define NT1   (HDIM / 128)    // 21 col-tiles in gemm1
#define NT2   (DDIM / 256)    // 3 col-tiles in gemm2

__device__ __forceinline__ void async_copy16(const void* g, void* l) {
    __builtin_amdgcn_global_load_lds(
        (__attribute__((address_space(1))) void*)g,
        (__attribute__((address_space(3))) void*)l,
        16, 0, 0);
}

// ---------------- Router ----------------
__global__ void router_kernel(const float* __restrict__ x,
                              const float* __restrict__ gate_w,
                              const float* __restrict__ ebias,
                              int* __restrict__ ctrl,
                              int* __restrict__ tok_e,
                              float* __restrict__ tok_w,
                              float* __restrict__ zloss) {
    __shared__ float gw[NEXP * DDIM];
    int tid = threadIdx.x;
    for (int i = tid; i < NEXP * DDIM; i += 256) gw[i] = gate_w[i];
    __syncthreads();

    int wv = tid >> 6, lane = tid & 63;
    int t = blockIdx.x * 4 + wv;
    const float* xr = x + (size_t)t * DDIM;

    float xv[12];
#pragma unroll
    for (int j = 0; j < 12; ++j) xv[j] = xr[j * 64 + lane];

    float acc[NEXP];
#pragma unroll
    for (int e = 0; e < NEXP; ++e) {
        float a = 0.f;
#pragma unroll
        for (int j = 0; j < 12; ++j) a += xv[j] * gw[e * DDIM + j * 64 + lane];
        acc[e] = a;
    }
#pragma unroll
    for (int e = 0; e < NEXP; ++e) {
#pragma unroll
        for (int off = 32; off > 0; off >>= 1) acc[e] += __shfl_xor(acc[e], off);
    }

    if (lane == 0) {
        float b[NEXP];
#pragma unroll
        for (int e = 0; e < NEXP; ++e) b[e] = acc[e] + ebias[e];
        int i0 = 0;
#pragma unroll
        for (int e = 1; e < NEXP; ++e) if (b[e] > b[i0]) i0 = e;
        int i1 = (i0 == 0) ? 1 : 0;
        float b1 = b[i1];
#pragma unroll
        for (int e = 0; e < NEXP; ++e) if (e != i0 && b[e] > b1) { b1 = b[e]; i1 = e; }

        float l0 = acc[i0], l1 = acc[i1];
        float mx = fmaxf(l0, l1);
        float e0 = __expf(l0 - mx), e1 = __expf(l1 - mx);
        float inv = 1.f / (e0 + e1);
        tok_e[t * 2 + 0] = i0;
        tok_e[t * 2 + 1] = i1;
        tok_w[t * 2 + 0] = e0 * inv;
        tok_w[t * 2 + 1] = e1 * inv;
        atomicAdd(&ctrl[i0], 1);
        atomicAdd(&ctrl[i1], 1);

        float m8 = acc[0];
#pragma unroll
        for (int e = 1; e < NEXP; ++e) m8 = fmaxf(m8, acc[e]);
        float s = 0.f;
#pragma unroll
        for (int e = 0; e < NEXP; ++e) s += __expf(acc[e] - m8);
        float lse = m8 + __logf(s);
        atomicAdd(zloss, (1e-5f / (float)T_TOK) * lse * lse);
    }
}

__global__ void offsets_kernel(int* ctrl) {
    if (threadIdx.x == 0 && blockIdx.x == 0) {
        int off = 0;
        for (int e = 0; e < NEXP; ++e) {
            ctrl[16 + e] = off;
            off += (ctrl[e] + 127) & ~127;
        }
        ctrl[16 + NEXP] = off;
    }
}

__global__ void scatter_kernel(int* __restrict__ ctrl,
                               const int* __restrict__ tok_e,
                               const float* __restrict__ tok_w,
                               int* __restrict__ pair_tok,
                               int* __restrict__ tok_pos) {
    int t = blockIdx.x * 256 + threadIdx.x;
    if (t >= T_TOK) return;
#pragma unroll
    for (int k = 0; k < 2; ++k) {
        int e = tok_e[t * 2 + k];
        int pos = ctrl[16 + e] + atomicAdd(&ctrl[8 + e], 1);
        pair_tok[pos] = t;
        tok_pos[t * 2 + k] = pos;
    }
}

__global__ void gather_kernel(const float* __restrict__ x,
                              const int* __restrict__ ctrl,
                              const int* __restrict__ pair_tok,
                              bf16* __restrict__ Xg) {
    int r = blockIdx.x;
    int tid = threadIdx.x;  // 192 threads, 4 floats each
    const int* offs = ctrl + 16;
    int total = offs[8];
    int tok = -1;
    if (r < total) {
        int e = 0;
#pragma unroll
        for (int i = 1; i < NEXP; ++i) if (r >= offs[i]) e = i;
        if (r - offs[e] < ctrl[e]) tok = pair_tok[r];
    }
    bf16x4 o;
    if (tok >= 0) {
        float4 v = *(const float4*)(x + (size_t)tok * DDIM + tid * 4);
        o.x = (bf16)v.x; o.y = (bf16)v.y; o.z = (bf16)v.z; o.w = (bf16)v.w;
    } else {
        o.x = (bf16)0.f; o.y = (bf16)0.f; o.z = (bf16)0.f; o.w = (bf16)0.f;
    }
    *(bf16x4*)(Xg + (size_t)r * DDIM + tid * 4) = o;
}

// ---------------- Weight transpose fp32->bf16 ----------------
__global__ void transpose_kernel(const float* __restrict__ wgp,
                                 const float* __restrict__ wup,
                                 const float* __restrict__ wdp,
                                 bf16* __restrict__ WgT,
                                 bf16* __restrict__ WuT,
                                 bf16* __restrict__ WdT) {
    __shared__ float tile[64][65];
    int m = blockIdx.y;
    int kind = m >> 3, e = m & 7;
    const float* src; bf16* dst; int R, C;
    if (kind == 0)      { src = wgp + (size_t)e * DDIM * HDIM; dst = WgT + (size_t)e * HDIM * DDIM; R = DDIM; C = HDIM; }
    else if (kind == 1) { src = wup + (size_t)e * DDIM * HDIM; dst = WuT + (size_t)e * HDIM * DDIM; R = DDIM; C = HDIM; }
    else                { src = wdp + (size_t)e * HDIM * DDIM; dst = WdT + (size_t)e * DDIM * HDIM; R = HDIM; C = DDIM; }

    int nR = R >> 6;
    int t = blockIdx.x;
    int tr = t % nR, tc = t / nR;
    int r0 = tr << 6, c0 = tc << 6;
    int lane = threadIdx.x & 63, wv = threadIdx.x >> 6;
#pragma unroll
    for (int rr = wv; rr < 64; rr += 4)
        tile[rr][lane] = src[(size_t)(r0 + rr) * C + c0 + lane];
    __syncthreads();
    int half = lane >> 5, rp = (lane & 31) * 2;
#pragma unroll
    for (int cc0 = wv * 2; cc0 < 64; cc0 += 8) {
        int cc = cc0 + half;
        bf16x2 v;
        v.x = (bf16)tile[rp][cc];
        v.y = (bf16)tile[rp + 1][cc];
        *(bf16x2*)(dst + (size_t)(c0 + cc) * R + r0 + rp) = v;
    }
}

// ---------------- GEMM1: G = silu(Xg@Wg) * (Xg@Wu) ----------------
// 512 threads (8 waves). Tile: 128 rows x 128 cols of BOTH gate and up.
// Grid id: e = id&7 (XCD pin), mtile = (id>>3)&31, nt = id>>8.
__launch_bounds__(512, 4)
__global__ void gemm1_kernel(const bf16* __restrict__ Xg,
                             const bf16* __restrict__ WgT,
                             const bf16* __restrict__ WuT,
                             const int* __restrict__ ctrl,
                             bf16* __restrict__ G) {
    int id = blockIdx.x;
    int e = id & 7;
    int mtile = (id >> 3) & 31;
    int nt = id >> 8;
    const int* offs = ctrl + 16;
    int off_e = offs[e];
    int pad_cnt = offs[e + 1] - off_e;
    if (mtile * 128 >= pad_cnt) return;
    int row0 = off_e + mtile * 128;
    int n0 = nt * 128;

    __shared__ __align__(16) bf16 sA[2][128 * 32];
    __shared__ __align__(16) bf16 sBg[2][128 * 32];
    __shared__ __align__(16) bf16 sBu[2][128 * 32];

    int tid = threadIdx.x;
    int wv = tid >> 6, lane = tid & 63;
    int wm = wv & 1, wq = wv >> 1;          // wm: row half, wq: col quarter (32)
    int quad = lane >> 4, lm = lane & 15;

    int arow = tid >> 2, aseg = tid & 3;    // 128 rows x 4 segs
    int kc = (aseg ^ ((arow >> 1) & 3)) * 8;

    const bf16* Ab = Xg + (size_t)(row0 + arow) * DDIM + kc;
    const bf16* Bg = WgT + ((size_t)e * HDIM + n0 + arow) * DDIM + kc;
    const bf16* Bu = WuT + ((size_t)e * HDIM + n0 + arow) * DDIM + kc;

    bf16* dA  = &sA[0][0] + tid * 8;
    bf16* dBg = &sBg[0][0] + tid * 8;
    bf16* dBu = &sBu[0][0] + tid * 8;

    int swq = quad ^ ((lm >> 1) & 3);
    const bf16* fa = &sA[0][0] + (wm * 64 + lm) * 32 + swq * 8;
    const bf16* fg = &sBg[0][0] + (wq * 32 + lm) * 32 + swq * 8;
    const bf16* fu = &sBu[0][0] + (wq * 32 + lm) * 32 + swq * 8;

    f32x4 accg[4][2], accu[4][2];
#pragma unroll
    for (int mi = 0; mi < 4; ++mi)
#pragma unroll
        for (int ni = 0; ni < 2; ++ni) { accg[mi][ni] = 0.f; accu[mi][ni] = 0.f; }

    async_copy16(Ab, dA);
    async_copy16(Bg, dBg);
    async_copy16(Bu, dBu);

    const int NK = DDIM / 32;  // 24
#pragma unroll
    for (int ks = 0; ks < NK; ++ks) {
        __syncthreads();
        if (ks + 1 < NK) {
            int kk = (ks + 1) * 32;
            int bo = ((ks + 1) & 1) * 4096;
            async_copy16(Ab + kk, dA + bo);
            async_copy16(Bg + kk, dBg + bo);
            async_copy16(Bu + kk, dBu + bo);
        }
        int bo = (ks & 1) * 4096;
        bf16x8 af[4], bg[2], bu[2];
#pragma unroll
        for (int mi = 0; mi < 4; ++mi)
            af[mi] = *(const bf16x8*)(fa + bo + mi * 512);
#pragma unroll
        for (int ni = 0; ni < 2; ++ni) {
            bg[ni] = *(const bf16x8*)(fg + bo + ni * 512);
            bu[ni] = *(const bf16x8*)(fu + bo + ni * 512);
        }
#pragma unroll
        for (int mi = 0; mi < 4; ++mi)
#pragma unroll
            for (int ni = 0; ni < 2; ++ni) {
                accg[mi][ni] = __builtin_amdgcn_mfma_f32_16x16x32_bf16(af[mi], bg[ni], accg[mi][ni], 0, 0, 0);
                accu[mi][ni] = __builtin_amdgcn_mfma_f32_16x16x32_bf16(af[mi], bu[ni], accu[mi][ni], 0, 0, 0);
            }
    }

#pragma unroll
    for (int mi = 0; mi < 4; ++mi)
#pragma unroll
        for (int ni = 0; ni < 2; ++ni)
#pragma unroll
            for (int r = 0; r < 4; ++r) {
                float gg = accg[mi][ni][r];
                float u = accu[mi][ni][r];
                float val = (gg / (1.f + __expf(-gg))) * u;
                int rl = wm * 64 + mi * 16 + quad * 4 + r;
                int col = n0 + wq * 32 + ni * 16 + lm;
                G[(size_t)(row0 + rl) * HDIM + col] = (bf16)val;
            }
}

// ---------------- GEMM2: Y_s = G[:, s-half] @ Wd[s-half], bf16 partials ----------------
// 512 threads (8 waves). Tile: 128 rows x 256 cols. K-split 2.
// Grid id: e = id&7, mtile = (id>>3)&31, rest = id>>8: s = rest&1, nt = rest>>1.
__launch_bounds__(512, 4)
__global__ void gemm2_kernel(const bf16* __restrict__ G,
                             const bf16* __restrict__ WdT,
                             const int* __restrict__ ctrl,
                             bf16* __restrict__ Ya,
                             bf16* __restrict__ Yb) {
    int id = blockIdx.x;
    int e = id & 7;
    int mtile = (id >> 3) & 31;
    int rest = id >> 8;
    int s = rest & 1, nt = rest >> 1;
    const int* offs = ctrl + 16;
    int off_e = offs[e];
    int pad_cnt = offs[e + 1] - off_e;
    if (mtile * 128 >= pad_cnt) return;
    int row0 = off_e + mtile * 128;
    int n0 = nt * 256;

    __shared__ __align__(16) bf16 sA[2][128 * 32];
    __shared__ __align__(16) bf16 sB[2][256 * 32];

    int tid = threadIdx.x;
    int wv = tid >> 6, lane = tid & 63;
    int wm = wv & 1, wq = wv >> 1;          // wm: row half, wq: col quarter (64)
    int quad = lane >> 4, lm = lane & 15;

    int arow = tid >> 2, aseg = tid & 3;
    int kca = (aseg ^ ((arow >> 1) & 3)) * 8;
    const bf16* Ab = G + (size_t)(row0 + arow) * HDIM + s * KHALF + kca;
    bf16* dA = &sA[0][0] + tid * 8;

    // B: 256 cols x 32 = 1024 16B-chunks; thread handles u=tid and u=tid+512
    int brow1 = tid >> 1;                    // u = tid*? -- decompose u directly
    // u0 = tid, u1 = tid + 512
    int b0row = tid >> 2, b0seg = tid & 3;
    int b1row = (tid + 512) >> 2, b1seg = tid & 3;
    int kb0 = (b0seg ^ ((b0row >> 1) & 3)) * 8;
    int kb1 = (b1seg ^ ((b1row >> 1) & 3)) * 8;
    const bf16* Bb0 = WdT + ((size_t)e * DDIM + n0 + b0row) * HDIM + s * KHALF + kb0;
    const bf16* Bb1 = WdT + ((size_t)e * DDIM + n0 + b1row) * HDIM + s * KHALF + kb1;
    bf16* dB0 = &sB[0][0] + tid * 8;
    bf16* dB1 = &sB[0][0] + (tid + 512) * 8;
    (void)brow1;

    int swq = quad ^ ((lm >> 1) & 3);
    const bf16* fa = &sA[0][0] + (wm * 64 + lm) * 32 + swq * 8;
    const bf16* fb = &sB[0][0] + (wq * 64 + lm) * 32 + swq * 8;

    f32x4 acc[4][4];
#pragma unroll
    for (int mi = 0; mi < 4; ++mi)
#pragma unroll
        for (int ni = 0; ni < 4; ++ni) acc[mi][ni] = 0.f;

    async_copy16(Ab, dA);
    async_copy16(Bb0, dB0);
    async_copy16(Bb1, dB1);

    const int NK = KHALF / 32;  // 42
#pragma unroll
    for (int ks = 0; ks < NK; ++ks) {
        __syncthreads();
        if (ks + 1 < NK) {
            int kk = (ks + 1) * 32;
            int boA = ((ks + 1) & 1) * 4096;
            int boB = ((ks + 1) & 1) * 8192;
            async_copy16(Ab + kk, dA + boA);
            async_copy16(Bb0 + kk, dB0 + boB);
            async_copy16(Bb1 + kk, dB1 + boB);
        }
        int boA = (ks & 1) * 4096;
        int boB = (ks & 1) * 8192;
        bf16x8 af[4], bb[4];
#pragma unroll
        for (int mi = 0; mi < 4; ++mi)
            af[mi] = *(const bf16x8*)(fa + boA + mi * 512);
#pragma unroll
        for (int ni = 0; ni < 4; ++ni)
            bb[ni] = *(const bf16x8*)(fb + boB + ni * 512);
#pragma unroll
        for (int mi = 0; mi < 4; ++mi)
#pragma unroll
            for (int ni = 0; ni < 4; ++ni)
                acc[mi][ni] = __builtin_amdgcn_mfma_f32_16x16x32_bf16(af[mi], bb[ni], acc[mi][ni], 0, 0, 0);
    }

    bf16* Y = s ? Yb : Ya;
#pragma unroll
    for (int mi = 0; mi < 4; ++mi)
#pragma unroll
        for (int r = 0; r < 4; ++r) {
            int rl = wm * 64 + mi * 16 + quad * 4 + r;
#pragma unroll
            for (int ni = 0; ni < 4; ++ni) {
                int col = n0 + wq * 64 + ni * 16 + lm;
                Y[(size_t)(row0 + rl) * DDIM + col] = (bf16)acc[mi][ni][r];
            }
        }
}

// ---------------- Combine ----------------
__global__ void combine_kernel(const bf16* __restrict__ Ya,
                               const bf16* __restrict__ Yb,
                               const int* __restrict__ tok_pos,
                               const float* __restrict__ tok_w,
                               float* __restrict__ out) {
    int t = blockIdx.x;
    int i = threadIdx.x;           // 192 threads x 4 cols
    int p0 = tok_pos[t * 2 + 0], p1 = tok_pos[t * 2 + 1];
    float w0 = tok_w[t * 2 + 0], w1 = tok_w[t * 2 + 1];
    bf16x4 a0 = *(const bf16x4*)(Ya + (size_t)p0 * DDIM + i * 4);
    bf16x4 b0 = *(const bf16x4*)(Yb + (size_t)p0 * DDIM + i * 4);
    bf16x4 a1 = *(const bf16x4*)(Ya + (size_t)p1 * DDIM + i * 4);
    bf16x4 b1 = *(const bf16x4*)(Yb + (size_t)p1 * DDIM + i * 4);
    float4 o;
    o.x = w0 * ((float)a0.x + (float)b0.x) + w1 * ((float)a1.x + (float)b1.x);
    o.y = w0 * ((float)a0.y + (float)b0.y) + w1 * ((float)a1.y + (float)b1.y);
    o.z = w0 * ((float)a0.z + (float)b0.z) + w1 * ((float)a1.z + (float)b1.z);
    o.w = w0 * ((float)a0.w + (float)b0.w) + w1 * ((float)a1.w + (float)b1.w);
    *(float4*)(out + (size_t)t * DDIM + i * 4) = o;
}

extern "C" void kernel_launch(void* const* d_in, const int* in_sizes, int n_in,
                              void* d_out, int out_size, void* d_ws, size_t ws_size,
                              hipStream_t stream) {
    const float* x      = (const float*)d_in[0];
    const float* gate_w = (const float*)d_in[1];
    const float* ebias  = (const float*)d_in[2];
    const float* wgp    = (const float*)d_in[3];
    const float* wup    = (const float*)d_in[4];
    const float* wdp    = (const float*)d_in[5];
    float* out = (float*)d_out;

    int*   ctrl     = (int*)d_ws;                          // 128 ints
    int*   tok_e    = ctrl + 128;                          // 2T
    float* tok_w    = (float*)(tok_e + 2 * T_TOK);         // 2T
    int*   pair_tok = (int*)(tok_w + 2 * T_TOK);           // RMAX
    int*   tok_pos  = pair_tok + RMAX;                     // 2T
    bf16*  Xg       = (bf16*)(tok_pos + 2 * T_TOK);        // RMAX*768 (reused as Ya)
    bf16*  Ya       = Xg;
    bf16*  Yb       = Xg + (size_t)RMAX * DDIM;            // RMAX*768
    bf16*  G        = Yb + (size_t)RMAX * DDIM;            // RMAX*2688
    bf16*  WgT      = G + (size_t)RMAX * HDIM;
    bf16*  WuT      = WgT + (size_t)NEXP * DDIM * HDIM;
    bf16*  WdT      = WuT + (size_t)NEXP * DDIM * HDIM;

    hipMemsetAsync(out + (size_t)T_TOK * DDIM, 0, sizeof(float), stream);  // z_loss
    hipMemsetAsync(d_ws, 0, 512, stream);                                  // ctrl

    router_kernel<<<T_TOK / 4, 256, 0, stream>>>(x, gate_w, ebias, ctrl, tok_e, tok_w,
                                                 out + (size_t)T_TOK * DDIM);
    offsets_kernel<<<1, 64, 0, stream>>>(ctrl);
    scatter_kernel<<<T_TOK / 256, 256, 0, stream>>>(ctrl, tok_e, tok_w, pair_tok, tok_pos);
    transpose_kernel<<<dim3(504, 24), 256, 0, stream>>>(wgp, wup, wdp, WgT, WuT, WdT);
    gather_kernel<<<RMAX, 192, 0, stream>>>(x, ctrl, pair_tok, Xg);
    gemm1_kernel<<<8 * 32 * NT1, 512, 0, stream>>>(Xg, WgT, WuT, ctrl, G);
    gemm2_kernel<<<8 * 32 * 2 * NT2, 512, 0, stream>>>(G, WdT, ctrl, Ya, Yb);
    combine_kernel<<<T_TOK, 192, 0, stream>>>(Ya, Yb, tok_pos, tok_w, out);
}